// Round 15
// baseline (217.782 us; speedup 1.0000x reference)
//
#include <hip/hip_runtime.h>
#include <hip/hip_bf16.h>
#include <hip/hip_fp16.h>

#define HID 64
#define NEG_SLOPE 0.2f
#define BLK_E 4096        // edges per block in binning passes
#define EDGE_CAP 6144     // LDS edge cache per bin
#define NDB 16            // blocks for degree sort

typedef _Float16 f16x2 __attribute__((ext_vector_type(2)));
typedef _Float16 f16x8 __attribute__((ext_vector_type(8)));
typedef float f32x4 __attribute__((ext_vector_type(4)));

// ============ counting-sort CSR build (no global atomics) ============

__global__ void k_hist2(const int* __restrict__ src, const int* __restrict__ dst,
                        int* __restrict__ histS, int* __restrict__ histD,
                        int E, int NB, int NBLK) {
    __shared__ int hs[512], hd[512];
    int t = threadIdx.x, blk = blockIdx.x;
    for (int b = t; b < NB; b += 1024) { hs[b] = 0; hd[b] = 0; }
    __syncthreads();
    int base = blk * BLK_E;
    #pragma unroll
    for (int k = 0; k < BLK_E / 1024; ++k) {
        int i = base + k * 1024 + t;
        if (i < E) {
            atomicAdd(&hs[src[i] >> 8], 1);
            atomicAdd(&hd[dst[i] >> 8], 1);
        }
    }
    __syncthreads();
    for (int b = t; b < NB; b += 1024) {
        histS[b * NBLK + blk] = hs[b];
        histD[b * NBLK + blk] = hd[b];
    }
}

// per-bin scan over blocks (NBLK <= 512)
__global__ void k_binscan(int* __restrict__ histS, int* __restrict__ histD,
                          int* __restrict__ totS, int* __restrict__ totD,
                          int NB, int NBLK) {
    __shared__ int s[512];
    int b = blockIdx.x;
    int* hist = histS; int* tot = totS;
    if (b >= NB) { b -= NB; hist = histD; tot = totD; }
    int t = threadIdx.x;
    int v = (t < NBLK) ? hist[b * NBLK + t] : 0;
    s[t] = v;
    __syncthreads();
    for (int o = 1; o < 512; o <<= 1) {
        int u = (t >= o) ? s[t - o] : 0;
        __syncthreads();
        s[t] += u;
        __syncthreads();
    }
    if (t < NBLK) hist[b * NBLK + t] = s[t] - v;
    if (t == 511) tot[b] = s[511];
}

__global__ void k_binoffset(const int* __restrict__ totS, const int* __restrict__ totD,
                            int* __restrict__ bsS, int* __restrict__ bsD,
                            int NB, int E, int* __restrict__ row_off, int N) {
    __shared__ int s[512];
    int t = threadIdx.x;
    int v = (t < NB) ? totS[t] : 0;
    s[t] = v; __syncthreads();
    for (int o = 1; o < 512; o <<= 1) {
        int u = (t >= o) ? s[t - o] : 0;
        __syncthreads(); s[t] += u; __syncthreads();
    }
    if (t < NB) bsS[t] = s[t] - v;
    if (t == 0) bsS[NB] = E;
    __syncthreads();
    v = (t < NB) ? totD[t] : 0;
    s[t] = v; __syncthreads();
    for (int o = 1; o < 512; o <<= 1) {
        int u = (t >= o) ? s[t - o] : 0;
        __syncthreads(); s[t] += u; __syncthreads();
    }
    if (t < NB) bsD[t] = s[t] - v;
    if (t == 0) { bsD[NB] = E; row_off[N] = E; }
}

__global__ void k_scatter_bins(const int* __restrict__ src, const int* __restrict__ dst,
                               const int* __restrict__ histS, const int* __restrict__ histD,
                               const int* __restrict__ bsS, const int* __restrict__ bsD,
                               unsigned* __restrict__ packS, unsigned* __restrict__ packD,
                               int E, int NB, int NBLK) {
    __shared__ int baseS[512], baseD[512];
    int t = threadIdx.x, blk = blockIdx.x;
    for (int b = t; b < NB; b += 1024) {
        baseS[b] = bsS[b] + histS[b * NBLK + blk];
        baseD[b] = bsD[b] + histD[b * NBLK + blk];
    }
    __syncthreads();
    int base = blk * BLK_E;
    #pragma unroll
    for (int k = 0; k < BLK_E / 1024; ++k) {
        int i = base + k * 1024 + t;
        if (i < E) {
            int sv = src[i], dv = dst[i];
            int pD = atomicAdd(&baseD[dv >> 8], 1);
            packD[pD] = ((unsigned)(dv & 255) << 24) | (unsigned)sv;
            int pS = atomicAdd(&baseS[sv >> 8], 1);
            packS[pS] = (unsigned)(sv & 255);
        }
    }
}

// fused: per-bin CSR finalize (deg_in, row_off, sorted csr_src) + src-side count
// (deg_out) + layer-1 transforms (A,B fp16) for the bin's 256 nodes.
__global__ void k_csr_bin_fused(const unsigned* __restrict__ packD, const int* __restrict__ bsD,
                                const unsigned* __restrict__ packS, const int* __restrict__ bsS,
                                int* __restrict__ row_off, float* __restrict__ deg_in,
                                int* __restrict__ csr_src,
                                const float* __restrict__ x,
                                const float* __restrict__ Wl, const float* __restrict__ bl,
                                const float* __restrict__ Wr, const float* __restrict__ br,
                                __half* __restrict__ A, __half* __restrict__ B, int N) {
    __shared__ int cnt[256], off[256], cur[256], cntS[256];
    __shared__ unsigned eb[EDGE_CAP];
    int b = blockIdx.x, t = threadIdx.x;
    int lo = bsD[b], hi = bsD[b + 1], ne = hi - lo;
    bool fits = (ne <= EDGE_CAP);
    if (t < 256) { cnt[t] = 0; cntS[t] = 0; }
    __syncthreads();
    for (int i = t; i < ne; i += 1024) {
        unsigned v = packD[lo + i];
        if (fits) eb[i] = v;
        atomicAdd(&cnt[v >> 24], 1);
    }
    int loS = bsS[b], hiS = bsS[b + 1];
    for (int i = loS + t; i < hiS; i += 1024) atomicAdd(&cntS[packS[i] & 255], 1);
    __syncthreads();
    if (t < 256) off[t] = cnt[t];
    __syncthreads();
    for (int o = 1; o < 256; o <<= 1) {
        int u = 0;
        if (t < 256 && t >= o) u = off[t - o];
        __syncthreads();
        if (t < 256) off[t] += u;
        __syncthreads();
    }
    if (t < 256) {
        int ex = off[t] - cnt[t];
        cur[t] = lo + ex;
        int node = b * 256 + t;
        if (node < N) {
            row_off[node] = lo + ex;
            deg_in[node] = (float)cnt[t];
        }
    }
    __syncthreads();
    for (int i = t; i < ne; i += 1024) {
        unsigned v = fits ? eb[i] : packD[lo + i];
        int pos = atomicAdd(&cur[v >> 24], 1);
        csr_src[pos] = (int)(v & 0xFFFFFFu);
    }
    // ---- fused layer-1 transform for this bin's nodes ----
    int nd = b * 256 + (t >> 2);
    if (nd < N) {
        float h0 = x[nd];
        float h1 = (float)cnt[t >> 2];
        float h2 = (float)cntS[t >> 2];
        int c0 = (t & 3) * 16;
        unsigned ua[4], ub[4];
        #pragma unroll
        for (int p = 0; p < 2; ++p) {
            #pragma unroll
            for (int q = 0; q < 4; ++q) {
                int c = c0 + p * 8 + q * 2;
                float a0 = h0 * Wl[c]     + h1 * Wl[64 + c]     + h2 * Wl[128 + c]     + bl[c];
                float a1 = h0 * Wl[c + 1] + h1 * Wl[64 + c + 1] + h2 * Wl[128 + c + 1] + bl[c + 1];
                float b0 = h0 * Wr[c]     + h1 * Wr[64 + c]     + h2 * Wr[128 + c]     + br[c];
                float b1 = h0 * Wr[c + 1] + h1 * Wr[64 + c + 1] + h2 * Wr[128 + c + 1] + br[c + 1];
                f16x2 pa; pa.x = (_Float16)a0; pa.y = (_Float16)a1;
                f16x2 pb; pb.x = (_Float16)b0; pb.y = (_Float16)b1;
                ua[q] = __builtin_bit_cast(unsigned, pa);
                ub[q] = __builtin_bit_cast(unsigned, pb);
            }
            uint4 sa = make_uint4(ua[0], ua[1], ua[2], ua[3]);
            uint4 sb = make_uint4(ub[0], ub[1], ub[2], ub[3]);
            ((uint4*)A)[(size_t)nd * 8 + (t & 3) * 2 + p] = sa;
            ((uint4*)B)[(size_t)nd * 8 + (t & 3) * 2 + p] = sb;
        }
    }
}

// ============ degree sort (perm only changes scheduling, not any FP result) ============

__global__ void k_deghist(const float* __restrict__ deg_in, int* __restrict__ dhist, int N) {
    __shared__ int h[64];
    int t = threadIdx.x, b = blockIdx.x;
    if (t < 64) h[t] = 0;
    __syncthreads();
    int chunk = (N + NDB - 1) / NDB;
    int lo = b * chunk, hi = lo + chunk; if (hi > N) hi = N;
    for (int i = lo + t; i < hi; i += 1024) {
        int dg = (int)deg_in[i]; if (dg > 63) dg = 63;
        atomicAdd(&h[dg], 1);
    }
    __syncthreads();
    if (t < 64) dhist[t * NDB + b] = h[t];
}

__global__ void k_degscan(int* __restrict__ dhist) {
    __shared__ int s[1024];
    int t = threadIdx.x;
    int v = dhist[t];
    s[t] = v; __syncthreads();
    for (int o = 1; o < 1024; o <<= 1) {
        int u = (t >= o) ? s[t - o] : 0;
        __syncthreads(); s[t] += u; __syncthreads();
    }
    dhist[t] = s[t] - v;
}

__global__ void k_degscatter(const float* __restrict__ deg_in, const int* __restrict__ dhist,
                             int* __restrict__ perm, int N) {
    __shared__ int cur[64];
    int t = threadIdx.x, b = blockIdx.x;
    if (t < 64) cur[t] = dhist[t * NDB + b];
    __syncthreads();
    int chunk = (N + NDB - 1) / NDB;
    int lo = b * chunk, hi = lo + chunk; if (hi > N) hi = N;
    for (int i = lo + t; i < hi; i += 1024) {
        int dg = (int)deg_in[i]; if (dg > 63) dg = 63;
        int p = atomicAdd(&cur[dg], 1);
        perm[p] = i;
    }
}

// ============ fused GAT layer: 16 lanes per dst node = 2 subgroups of 8,
// each with an independent online softmax over half the edges, merged at end ============

struct H4 { f16x2 h[4]; };

__device__ __forceinline__ f16x2 bch2(unsigned u) {
    return __builtin_bit_cast(f16x2, u);
}

__device__ __forceinline__ H4 ld4(const uint4* __restrict__ T, size_t idx) {
    uint4 r = T[idx];
    H4 o;
    o.h[0] = bch2(r.x); o.h[1] = bch2(r.y); o.h[2] = bch2(r.z); o.h[3] = bch2(r.w);
    return o;
}

// 8-channel partial logit
__device__ __forceinline__ float logit8(const H4& a, const H4& x,
                                        const float* __restrict__ awf, f16x2 ns2) {
    float t = 0.0f;
    #pragma unroll
    for (int j = 0; j < 4; ++j) {
        f16x2 s = a.h[j] + x.h[j];
        f16x2 l = __builtin_elementwise_max(s, ns2 * s);
        t = fmaf((float)l.x, awf[2 * j], t);
        t = fmaf((float)l.y, awf[2 * j + 1], t);
    }
    return t;
}

__device__ __forceinline__ void accum8(float* __restrict__ acc, const H4& a, float w) {
    #pragma unroll
    for (int j = 0; j < 4; ++j) {
        acc[2 * j]     = fmaf((float)a.h[j].x, w, acc[2 * j]);
        acc[2 * j + 1] = fmaf((float)a.h[j].y, w, acc[2 * j + 1]);
    }
}

template <typename OUT, bool TANH>
__global__ void k_gat_fused(const int* __restrict__ csr_src, const int* __restrict__ row_off,
                            const int* __restrict__ perm,
                            const __half* __restrict__ Ah, const __half* __restrict__ Bh,
                            const float* __restrict__ aw, const float* __restrict__ bias,
                            OUT* __restrict__ out, int N) {
    int tid = blockIdx.x * blockDim.x + threadIdx.x;
    int r = tid >> 4;                 // node slot (16 lanes)
    int sub = (threadIdx.x >> 3) & 1; // subgroup: 0 = first half + self loop, 1 = second half
    int gl = threadIdx.x & 7;         // lane in subgroup (8 channels each)
    if (r >= N) return;
    int d = perm[N - 1 - r];          // descending degree

    const uint4* A16 = (const uint4*)Ah;
    const uint4* B16 = (const uint4*)Bh;
    f16x2 ns2;
    ns2.x = (_Float16)NEG_SLOPE; ns2.y = (_Float16)NEG_SLOPE;

    float awf[8], bw[8];
    {
        const float4* a4 = (const float4*)aw;
        const float4* b4 = (const float4*)bias;
        #pragma unroll
        for (int j = 0; j < 2; ++j) {
            float4 v = a4[gl * 2 + j];
            awf[4 * j] = v.x; awf[4 * j + 1] = v.y; awf[4 * j + 2] = v.z; awf[4 * j + 3] = v.w;
            float4 u = b4[gl * 2 + j];
            bw[4 * j] = u.x; bw[4 * j + 1] = u.y; bw[4 * j + 2] = u.z; bw[4 * j + 3] = u.w;
        }
    }

    size_t rowbase = (size_t)d * 8 + gl;
    H4 xh = ld4(B16, rowbase);

    float m = -1e30f, denom = 0.0f;
    float acc[8] = {0, 0, 0, 0, 0, 0, 0, 0};

    if (sub == 0) {
        // self loop seeds subgroup 0's online-softmax state
        H4 as = ld4(A16, rowbase);
        float t = logit8(as, xh, awf, ns2);
        t += __shfl_xor(t, 1); t += __shfl_xor(t, 2); t += __shfl_xor(t, 4);
        m = t; denom = 1.0f;
        #pragma unroll
        for (int j = 0; j < 4; ++j) {
            acc[2 * j] = (float)as.h[j].x;
            acc[2 * j + 1] = (float)as.h[j].y;
        }
    }

    int lo = row_off[d], hi = row_off[d + 1];
    int len = hi - lo, half = (len + 1) >> 1;
    int k   = sub ? lo + half : lo;
    int khi = sub ? hi : lo + half;
    for (; k + 3 < khi; k += 4) {
        int s0 = csr_src[k], s1 = csr_src[k + 1], s2 = csr_src[k + 2], s3 = csr_src[k + 3];
        H4 a0 = ld4(A16, (size_t)s0 * 8 + gl);
        H4 a1 = ld4(A16, (size_t)s1 * 8 + gl);
        H4 a2 = ld4(A16, (size_t)s2 * 8 + gl);
        H4 a3 = ld4(A16, (size_t)s3 * 8 + gl);
        float t0 = logit8(a0, xh, awf, ns2);
        float t1 = logit8(a1, xh, awf, ns2);
        float t2 = logit8(a2, xh, awf, ns2);
        float t3 = logit8(a3, xh, awf, ns2);
        t0 += __shfl_xor(t0, 1); t1 += __shfl_xor(t1, 1);
        t2 += __shfl_xor(t2, 1); t3 += __shfl_xor(t3, 1);
        t0 += __shfl_xor(t0, 2); t1 += __shfl_xor(t1, 2);
        t2 += __shfl_xor(t2, 2); t3 += __shfl_xor(t3, 2);
        t0 += __shfl_xor(t0, 4); t1 += __shfl_xor(t1, 4);
        t2 += __shfl_xor(t2, 4); t3 += __shfl_xor(t3, 4);
        float mx = fmaxf(fmaxf(t0, t1), fmaxf(t2, t3));
        if (mx > m) {
            float sc = __expf(m - mx);
            denom *= sc;
            #pragma unroll
            for (int j = 0; j < 8; ++j) acc[j] *= sc;
            m = mx;
        }
        float w0 = __expf(t0 - m), w1 = __expf(t1 - m);
        float w2 = __expf(t2 - m), w3 = __expf(t3 - m);
        denom += (w0 + w1) + (w2 + w3);
        accum8(acc, a0, w0);
        accum8(acc, a1, w1);
        accum8(acc, a2, w2);
        accum8(acc, a3, w3);
    }
    for (; k < khi; ++k) {
        int s0 = csr_src[k];
        H4 a0 = ld4(A16, (size_t)s0 * 8 + gl);
        float t0 = logit8(a0, xh, awf, ns2);
        t0 += __shfl_xor(t0, 1); t0 += __shfl_xor(t0, 2); t0 += __shfl_xor(t0, 4);
        if (t0 > m) {
            float sc = __expf(m - t0);
            denom *= sc;
            #pragma unroll
            for (int j = 0; j < 8; ++j) acc[j] *= sc;
            m = t0;
        }
        float w0 = __expf(t0 - m);
        denom += w0;
        accum8(acc, a0, w0);
    }

    // merge the two subgroup softmax states (lanes gl and gl+8 hold same channels)
    {
        float mo = __shfl_xor(m, 8);
        float no = __shfl_xor(denom, 8);
        float M = fmaxf(m, mo);
        float s0 = __expf(m - M);
        float s1 = __expf(mo - M);
        denom = denom * s0 + no * s1;
        #pragma unroll
        for (int j = 0; j < 8; ++j) {
            float ao = __shfl_xor(acc[j], 8);
            acc[j] = acc[j] * s0 + ao * s1;
        }
    }

    float inv = 1.0f / denom;
    float v[8];
    #pragma unroll
    for (int j = 0; j < 8; ++j) {
        v[j] = acc[j] * inv + bw[j];
        if (TANH) v[j] = tanhf(v[j]);
    }
    if (sub == 0) {
        if constexpr (sizeof(OUT) == 2) {
            unsigned u[4];
            #pragma unroll
            for (int j = 0; j < 4; ++j) {
                f16x2 p; p.x = (_Float16)v[2 * j]; p.y = (_Float16)v[2 * j + 1];
                u[j] = __builtin_bit_cast(unsigned, p);
            }
            ((uint4*)out)[(size_t)d * 8 + gl] = make_uint4(u[0], u[1], u[2], u[3]);
        } else {
            float4* o4 = (float4*)out;
            o4[(size_t)d * 16 + gl * 2]     = make_float4(v[0], v[1], v[2], v[3]);
            o4[(size_t)d * 16 + gl * 2 + 1] = make_float4(v[4], v[5], v[6], v[7]);
        }
    }
}

// ============ layer-2 transforms via MFMA ============

// prep: W (64x64 fp32, [k][c]) -> Wt (fp16, [c][k]) for B^T fragment loads
__global__ void k_wprep(const float* __restrict__ Wl, const float* __restrict__ Wr,
                        __half* __restrict__ Wtl, __half* __restrict__ Wtr) {
    int t = blockIdx.x * blockDim.x + threadIdx.x;
    if (t < 4096) {
        int c = t & 63, k = t >> 6;
        Wtl[(size_t)c * 64 + k] = __float2half(Wl[k * 64 + c]);
        Wtr[(size_t)c * 64 + k] = __float2half(Wr[k * 64 + c]);
    }
}

// each wave: 16 nodes x 64 ch for both tables; 16 x mfma_f32_16x16x32_f16.
__global__ __launch_bounds__(256) void k_xfrm2_mfma(
        const __half* __restrict__ H,
        const __half* __restrict__ Wtl, const __half* __restrict__ Wtr,
        const float* __restrict__ bl, const float* __restrict__ br,
        __half* __restrict__ A, __half* __restrict__ B, int N) {
    int wid = threadIdx.x >> 6;
    int lane = threadIdx.x & 63;
    int n0 = (blockIdx.x * 4 + wid) * 16;
    if (n0 >= N) return;
    int row = lane & 15, kg = lane >> 4;
    int nrow = n0 + row; if (nrow >= N) nrow = N - 1;   // clamp (loads only)

    const uint4* Hp = (const uint4*)(H + (size_t)nrow * HID + kg * 8);
    f16x8 af0 = __builtin_bit_cast(f16x8, Hp[0]);       // k = kg*8 .. +7
    f16x8 af1 = __builtin_bit_cast(f16x8, Hp[4]);       // k = 32 + kg*8 .. +7

    #pragma unroll
    for (int tb = 0; tb < 2; ++tb) {
        const __half* Wt = tb ? Wtr : Wtl;
        const float* bb  = tb ? br : bl;
        __half* OT       = tb ? B : A;
        #pragma unroll
        for (int ct = 0; ct < 4; ++ct) {
            int c = ct * 16 + row;
            const uint4* Wp = (const uint4*)(Wt + (size_t)c * HID + kg * 8);
            f16x8 bf0 = __builtin_bit_cast(f16x8, Wp[0]);
            f16x8 bf1 = __builtin_bit_cast(f16x8, Wp[4]);
            f32x4 acc = {0.f, 0.f, 0.f, 0.f};
            acc = __builtin_amdgcn_mfma_f32_16x16x32_f16(af0, bf0, acc, 0, 0, 0);
            acc = __builtin_amdgcn_mfma_f32_16x16x32_f16(af1, bf1, acc, 0, 0, 0);
            float bias = bb[c];
            #pragma unroll
            for (int r = 0; r < 4; ++r) {
                int node = n0 + kg * 4 + r;
                if (node < N) OT[(size_t)node * HID + c] = __float2half(acc[r] + bias);
            }
        }
    }
}

// fused pool + final linear: one wave per graph; binary-search bounds from sorted batch
__global__ void k_pool_final(const __half* __restrict__ C, const float* __restrict__ b2,
                             const int* __restrict__ batch,
                             const float* __restrict__ W3, const float* __restrict__ b3,
                             float* __restrict__ out, int N, int G) {
    int w = (int)((blockIdx.x * (size_t)blockDim.x + threadIdx.x) >> 6);
    int lane = threadIdx.x & 63;
    if (w >= G) return;
    int lo = 0, hi = N;
    while (lo < hi) { int mid = (lo + hi) >> 1; if (batch[mid] < w) lo = mid + 1; else hi = mid; }
    int s0 = lo;
    hi = N;
    while (lo < hi) { int mid = (lo + hi) >> 1; if (batch[mid] < w + 1) lo = mid + 1; else hi = mid; }
    int e0 = lo;

    float acc = -INFINITY;
    int i = s0;
    for (; i + 3 < e0; i += 4) {
        float v0 = __half2float(C[(size_t)i * HID + lane]);
        float v1 = __half2float(C[(size_t)(i + 1) * HID + lane]);
        float v2 = __half2float(C[(size_t)(i + 2) * HID + lane]);
        float v3 = __half2float(C[(size_t)(i + 3) * HID + lane]);
        acc = fmaxf(acc, fmaxf(fmaxf(v0, v1), fmaxf(v2, v3)));
    }
    for (; i < e0; ++i) acc = fmaxf(acc, __half2float(C[(size_t)i * HID + lane]));
    float v = acc + b2[lane];

    float p0 = v * W3[lane * 2];
    float p1 = v * W3[lane * 2 + 1];
    #pragma unroll
    for (int o = 32; o; o >>= 1) { p0 += __shfl_xor(p0, o); p1 += __shfl_xor(p1, o); }
    if (lane == 0) {
        out[(size_t)w * 2]     = p0 + b3[0];
        out[(size_t)w * 2 + 1] = p1 + b3[1];
    }
}

extern "C" void kernel_launch(void* const* d_in, const int* in_sizes, int n_in,
                              void* d_out, int out_size, void* d_ws, size_t ws_size,
                              hipStream_t stream) {
    const float* x     = (const float*)d_in[0];
    const int*   ei    = (const int*)d_in[1];
    const int*   batch = (const int*)d_in[2];
    const float* Wl1 = (const float*)d_in[3];
    const float* bl1 = (const float*)d_in[4];
    const float* Wr1 = (const float*)d_in[5];
    const float* br1 = (const float*)d_in[6];
    const float* a1  = (const float*)d_in[7];
    const float* b1  = (const float*)d_in[8];
    const float* Wl2 = (const float*)d_in[9];
    const float* bl2 = (const float*)d_in[10];
    const float* Wr2 = (const float*)d_in[11];
    const float* br2 = (const float*)d_in[12];
    const float* a2  = (const float*)d_in[13];
    const float* b2  = (const float*)d_in[14];
    const float* W3  = (const float*)d_in[15];
    const float* b3  = (const float*)d_in[16];

    const int N = in_sizes[0];          // 100000
    const int E = in_sizes[1] / 2;      // 1600000
    const int G = out_size / 2;         // 1000
    const int NB = (N + 255) >> 8;                 // 391 node bins
    const int NBLK = (E + BLK_E - 1) / BLK_E;      // 391 edge blocks

    // ---- workspace layout ----
    float* ws = (float*)d_ws;
    size_t off = 0;
    float*  C  = ws + off; off += (size_t)N * HID;  // sort temporaries + fp16 C overlay
    __half* Ah = (__half*)(ws + off); off += (size_t)N * HID / 2;
    __half* Bh = (__half*)(ws + off); off += (size_t)N * HID / 2;
    int*   row_off = (int*)(ws + off); off += N + 1;
    int*   csr_src = (int*)(ws + off); off += E;
    float* deg_in  = ws + off; off += N;
    int*   perm    = (int*)(ws + off); off += N;
    int*   dhist   = (int*)(ws + off); off += 1024;
    int*   bsS  = (int*)(ws + off); off += NB + 1;
    int*   bsD  = (int*)(ws + off); off += NB + 1;
    int*   totS = (int*)(ws + off); off += NB;
    int*   totD = (int*)(ws + off); off += NB;
    off = (off + 3) & ~(size_t)3;                   // 16B align for fp16 uint4 loads
    __half* Wtl = (__half*)(ws + off); off += 2048;
    __half* Wtr = (__half*)(ws + off); off += 2048;

    unsigned* packD = (unsigned*)C;
    unsigned* packS = packD + E;
    int* histS = (int*)(packS + E);
    int* histD = histS + (size_t)NB * NBLK;
    __half* Chalf = (__half*)C;       // layer-1 & layer-2 node features (fp16)

    const int* src  = ei;
    const int* dstp = ei + E;

    const int BT = 256;
    dim3 blk(BT);
    int grid_g16 = (int)(((size_t)N * 16 + BT - 1) / BT);
    int grid_mf  = (N + 63) / 64;      // 4 waves/block x 16 nodes/wave

    // ---- CSR build via counting sort (no global atomics) ----
    k_hist2<<<NBLK, 1024, 0, stream>>>(src, dstp, histS, histD, E, NB, NBLK);
    k_binscan<<<2 * NB, 512, 0, stream>>>(histS, histD, totS, totD, NB, NBLK);
    k_binoffset<<<1, 512, 0, stream>>>(totS, totD, bsS, bsD, NB, E, row_off, N);
    k_scatter_bins<<<NBLK, 1024, 0, stream>>>(src, dstp, histS, histD, bsS, bsD,
                                              packS, packD, E, NB, NBLK);
    // fused: CSR finalize + deg_out count + layer-1 transforms
    k_csr_bin_fused<<<NB, 1024, 0, stream>>>(packD, bsD, packS, bsS, row_off, deg_in,
                                             csr_src, x, Wl1, bl1, Wr1, br1, Ah, Bh, N);

    // ---- degree-sorted node permutation (scheduling only) + W2 prep ----
    k_deghist<<<NDB, 1024, 0, stream>>>(deg_in, dhist, N);
    k_degscan<<<1, 1024, 0, stream>>>(dhist);
    k_degscatter<<<NDB, 1024, 0, stream>>>(deg_in, dhist, perm, N);
    k_wprep<<<16, 256, 0, stream>>>(Wl2, Wr2, Wtl, Wtr);

    // ---- layer 1 (fp16 output) ----
    k_gat_fused<__half, true><<<grid_g16, blk, 0, stream>>>(csr_src, row_off, perm,
                                                            Ah, Bh, a1, b1, Chalf, N);

    // ---- layer 2 (MFMA transforms, fp16 output) ----
    k_xfrm2_mfma<<<grid_mf, 256, 0, stream>>>(Chalf, Wtl, Wtr, bl2, br2, Ah, Bh, N);
    k_gat_fused<__half, false><<<grid_g16, blk, 0, stream>>>(csr_src, row_off, perm,
                                                             Ah, Bh, a2, b2, Chalf, N);

    // ---- fused pool + final linear ----
    k_pool_final<<<(G * 64 + BT - 1) / BT, blk, 0, stream>>>(Chalf, b2, batch, W3, b3,
                                                             (float*)d_out, N, G);
}

// Round 16
// 201.055 us; speedup vs baseline: 1.0832x; 1.0832x over previous
//
#include <hip/hip_runtime.h>
#include <hip/hip_bf16.h>
#include <hip/hip_fp16.h>

#define HID 64
#define NEG_SLOPE 0.2f
#define BLK_E 4096        // edges per block in binning passes
#define EDGE_CAP 6144     // LDS edge cache per bin
#define NDB 16            // blocks for degree sort

typedef _Float16 f16x2 __attribute__((ext_vector_type(2)));
typedef _Float16 f16x8 __attribute__((ext_vector_type(8)));
typedef float f32x4 __attribute__((ext_vector_type(4)));

// ============ counting-sort CSR build (no global atomics) ============

__global__ void k_hist2(const int* __restrict__ src, const int* __restrict__ dst,
                        int* __restrict__ histS, int* __restrict__ histD,
                        int E, int NB, int NBLK) {
    __shared__ int hs[512], hd[512];
    int t = threadIdx.x, blk = blockIdx.x;
    for (int b = t; b < NB; b += 1024) { hs[b] = 0; hd[b] = 0; }
    __syncthreads();
    int base = blk * BLK_E;
    #pragma unroll
    for (int k = 0; k < BLK_E / 1024; ++k) {
        int i = base + k * 1024 + t;
        if (i < E) {
            atomicAdd(&hs[src[i] >> 8], 1);
            atomicAdd(&hd[dst[i] >> 8], 1);
        }
    }
    __syncthreads();
    for (int b = t; b < NB; b += 1024) {
        histS[b * NBLK + blk] = hs[b];
        histD[b * NBLK + blk] = hd[b];
    }
}

// per-bin scan over blocks (NBLK <= 512)
__global__ void k_binscan(int* __restrict__ histS, int* __restrict__ histD,
                          int* __restrict__ totS, int* __restrict__ totD,
                          int NB, int NBLK) {
    __shared__ int s[512];
    int b = blockIdx.x;
    int* hist = histS; int* tot = totS;
    if (b >= NB) { b -= NB; hist = histD; tot = totD; }
    int t = threadIdx.x;
    int v = (t < NBLK) ? hist[b * NBLK + t] : 0;
    s[t] = v;
    __syncthreads();
    for (int o = 1; o < 512; o <<= 1) {
        int u = (t >= o) ? s[t - o] : 0;
        __syncthreads();
        s[t] += u;
        __syncthreads();
    }
    if (t < NBLK) hist[b * NBLK + t] = s[t] - v;
    if (t == 511) tot[b] = s[511];
}

__global__ void k_binoffset(const int* __restrict__ totS, const int* __restrict__ totD,
                            int* __restrict__ bsS, int* __restrict__ bsD,
                            int NB, int E, int* __restrict__ row_off, int N) {
    __shared__ int s[512];
    int t = threadIdx.x;
    int v = (t < NB) ? totS[t] : 0;
    s[t] = v; __syncthreads();
    for (int o = 1; o < 512; o <<= 1) {
        int u = (t >= o) ? s[t - o] : 0;
        __syncthreads(); s[t] += u; __syncthreads();
    }
    if (t < NB) bsS[t] = s[t] - v;
    if (t == 0) bsS[NB] = E;
    __syncthreads();
    v = (t < NB) ? totD[t] : 0;
    s[t] = v; __syncthreads();
    for (int o = 1; o < 512; o <<= 1) {
        int u = (t >= o) ? s[t - o] : 0;
        __syncthreads(); s[t] += u; __syncthreads();
    }
    if (t < NB) bsD[t] = s[t] - v;
    if (t == 0) { bsD[NB] = E; row_off[N] = E; }
}

__global__ void k_scatter_bins(const int* __restrict__ src, const int* __restrict__ dst,
                               const int* __restrict__ histS, const int* __restrict__ histD,
                               const int* __restrict__ bsS, const int* __restrict__ bsD,
                               unsigned* __restrict__ packS, unsigned* __restrict__ packD,
                               int E, int NB, int NBLK) {
    __shared__ int baseS[512], baseD[512];
    int t = threadIdx.x, blk = blockIdx.x;
    for (int b = t; b < NB; b += 1024) {
        baseS[b] = bsS[b] + histS[b * NBLK + blk];
        baseD[b] = bsD[b] + histD[b * NBLK + blk];
    }
    __syncthreads();
    int base = blk * BLK_E;
    #pragma unroll
    for (int k = 0; k < BLK_E / 1024; ++k) {
        int i = base + k * 1024 + t;
        if (i < E) {
            int sv = src[i], dv = dst[i];
            int pD = atomicAdd(&baseD[dv >> 8], 1);
            packD[pD] = ((unsigned)(dv & 255) << 24) | (unsigned)sv;
            int pS = atomicAdd(&baseS[sv >> 8], 1);
            packS[pS] = (unsigned)(sv & 255);
        }
    }
}

// fused: per-bin CSR finalize (deg_in, row_off, sorted csr_src) + src-side count
// (deg_out) + layer-1 transforms (A,B fp16) for the bin's 256 nodes.
__global__ void k_csr_bin_fused(const unsigned* __restrict__ packD, const int* __restrict__ bsD,
                                const unsigned* __restrict__ packS, const int* __restrict__ bsS,
                                int* __restrict__ row_off, float* __restrict__ deg_in,
                                int* __restrict__ csr_src,
                                const float* __restrict__ x,
                                const float* __restrict__ Wl, const float* __restrict__ bl,
                                const float* __restrict__ Wr, const float* __restrict__ br,
                                __half* __restrict__ A, __half* __restrict__ B, int N) {
    __shared__ int cnt[256], off[256], cur[256], cntS[256];
    __shared__ unsigned eb[EDGE_CAP];
    int b = blockIdx.x, t = threadIdx.x;
    int lo = bsD[b], hi = bsD[b + 1], ne = hi - lo;
    bool fits = (ne <= EDGE_CAP);
    if (t < 256) { cnt[t] = 0; cntS[t] = 0; }
    __syncthreads();
    for (int i = t; i < ne; i += 1024) {
        unsigned v = packD[lo + i];
        if (fits) eb[i] = v;
        atomicAdd(&cnt[v >> 24], 1);
    }
    int loS = bsS[b], hiS = bsS[b + 1];
    for (int i = loS + t; i < hiS; i += 1024) atomicAdd(&cntS[packS[i] & 255], 1);
    __syncthreads();
    if (t < 256) off[t] = cnt[t];
    __syncthreads();
    for (int o = 1; o < 256; o <<= 1) {
        int u = 0;
        if (t < 256 && t >= o) u = off[t - o];
        __syncthreads();
        if (t < 256) off[t] += u;
        __syncthreads();
    }
    if (t < 256) {
        int ex = off[t] - cnt[t];
        cur[t] = lo + ex;
        int node = b * 256 + t;
        if (node < N) {
            row_off[node] = lo + ex;
            deg_in[node] = (float)cnt[t];
        }
    }
    __syncthreads();
    for (int i = t; i < ne; i += 1024) {
        unsigned v = fits ? eb[i] : packD[lo + i];
        int pos = atomicAdd(&cur[v >> 24], 1);
        csr_src[pos] = (int)(v & 0xFFFFFFu);
    }
    // ---- fused layer-1 transform for this bin's nodes ----
    int nd = b * 256 + (t >> 2);
    if (nd < N) {
        float h0 = x[nd];
        float h1 = (float)cnt[t >> 2];
        float h2 = (float)cntS[t >> 2];
        int c0 = (t & 3) * 16;
        unsigned ua[4], ub[4];
        #pragma unroll
        for (int p = 0; p < 2; ++p) {
            #pragma unroll
            for (int q = 0; q < 4; ++q) {
                int c = c0 + p * 8 + q * 2;
                float a0 = h0 * Wl[c]     + h1 * Wl[64 + c]     + h2 * Wl[128 + c]     + bl[c];
                float a1 = h0 * Wl[c + 1] + h1 * Wl[64 + c + 1] + h2 * Wl[128 + c + 1] + bl[c + 1];
                float b0 = h0 * Wr[c]     + h1 * Wr[64 + c]     + h2 * Wr[128 + c]     + br[c];
                float b1 = h0 * Wr[c + 1] + h1 * Wr[64 + c + 1] + h2 * Wr[128 + c + 1] + br[c + 1];
                f16x2 pa; pa.x = (_Float16)a0; pa.y = (_Float16)a1;
                f16x2 pb; pb.x = (_Float16)b0; pb.y = (_Float16)b1;
                ua[q] = __builtin_bit_cast(unsigned, pa);
                ub[q] = __builtin_bit_cast(unsigned, pb);
            }
            uint4 sa = make_uint4(ua[0], ua[1], ua[2], ua[3]);
            uint4 sb = make_uint4(ub[0], ub[1], ub[2], ub[3]);
            ((uint4*)A)[(size_t)nd * 8 + (t & 3) * 2 + p] = sa;
            ((uint4*)B)[(size_t)nd * 8 + (t & 3) * 2 + p] = sb;
        }
    }
}

// ============ degree sort (perm only changes scheduling, not any FP result) ============

__global__ void k_deghist(const float* __restrict__ deg_in, int* __restrict__ dhist, int N) {
    __shared__ int h[64];
    int t = threadIdx.x, b = blockIdx.x;
    if (t < 64) h[t] = 0;
    __syncthreads();
    int chunk = (N + NDB - 1) / NDB;
    int lo = b * chunk, hi = lo + chunk; if (hi > N) hi = N;
    for (int i = lo + t; i < hi; i += 1024) {
        int dg = (int)deg_in[i]; if (dg > 63) dg = 63;
        atomicAdd(&h[dg], 1);
    }
    __syncthreads();
    if (t < 64) dhist[t * NDB + b] = h[t];
}

__global__ void k_degscan(int* __restrict__ dhist) {
    __shared__ int s[1024];
    int t = threadIdx.x;
    int v = dhist[t];
    s[t] = v; __syncthreads();
    for (int o = 1; o < 1024; o <<= 1) {
        int u = (t >= o) ? s[t - o] : 0;
        __syncthreads(); s[t] += u; __syncthreads();
    }
    dhist[t] = s[t] - v;
}

__global__ void k_degscatter(const float* __restrict__ deg_in, const int* __restrict__ dhist,
                             int* __restrict__ perm, int N) {
    __shared__ int cur[64];
    int t = threadIdx.x, b = blockIdx.x;
    if (t < 64) cur[t] = dhist[t * NDB + b];
    __syncthreads();
    int chunk = (N + NDB - 1) / NDB;
    int lo = b * chunk, hi = lo + chunk; if (hi > N) hi = N;
    for (int i = lo + t; i < hi; i += 1024) {
        int dg = (int)deg_in[i]; if (dg > 63) dg = 63;
        int p = atomicAdd(&cur[dg], 1);
        perm[p] = i;
    }
}

// ============ fused GAT layer: 8 lanes per dst node (8 ch each) ============

struct H4 { f16x2 h[4]; };

__device__ __forceinline__ f16x2 bch2(unsigned u) {
    return __builtin_bit_cast(f16x2, u);
}

__device__ __forceinline__ H4 ld4(const uint4* __restrict__ T, size_t idx) {
    uint4 r = T[idx];
    H4 o;
    o.h[0] = bch2(r.x); o.h[1] = bch2(r.y); o.h[2] = bch2(r.z); o.h[3] = bch2(r.w);
    return o;
}

// 8-channel partial logit
__device__ __forceinline__ float logit8(const H4& a, const H4& x,
                                        const float* __restrict__ awf, f16x2 ns2) {
    float t = 0.0f;
    #pragma unroll
    for (int j = 0; j < 4; ++j) {
        f16x2 s = a.h[j] + x.h[j];
        f16x2 l = __builtin_elementwise_max(s, ns2 * s);
        t = fmaf((float)l.x, awf[2 * j], t);
        t = fmaf((float)l.y, awf[2 * j + 1], t);
    }
    return t;
}

__device__ __forceinline__ void accum8(float* __restrict__ acc, const H4& a, float w) {
    #pragma unroll
    for (int j = 0; j < 4; ++j) {
        acc[2 * j]     = fmaf((float)a.h[j].x, w, acc[2 * j]);
        acc[2 * j + 1] = fmaf((float)a.h[j].y, w, acc[2 * j + 1]);
    }
}

template <typename OUT, bool TANH>
__global__ void k_gat_fused(const int* __restrict__ csr_src, const int* __restrict__ row_off,
                            const int* __restrict__ perm,
                            const __half* __restrict__ Ah, const __half* __restrict__ Bh,
                            const float* __restrict__ aw, const float* __restrict__ bias,
                            OUT* __restrict__ out, int N) {
    int tid = blockIdx.x * blockDim.x + threadIdx.x;
    int r = tid >> 3;
    int gl = threadIdx.x & 7;
    if (r >= N) return;
    int d = perm[N - 1 - r];   // descending degree

    const uint4* A16 = (const uint4*)Ah;
    const uint4* B16 = (const uint4*)Bh;
    f16x2 ns2;
    ns2.x = (_Float16)NEG_SLOPE; ns2.y = (_Float16)NEG_SLOPE;

    float awf[8], bw[8];
    {
        const float4* a4 = (const float4*)aw;
        const float4* b4 = (const float4*)bias;
        #pragma unroll
        for (int j = 0; j < 2; ++j) {
            float4 v = a4[gl * 2 + j];
            awf[4 * j] = v.x; awf[4 * j + 1] = v.y; awf[4 * j + 2] = v.z; awf[4 * j + 3] = v.w;
            float4 u = b4[gl * 2 + j];
            bw[4 * j] = u.x; bw[4 * j + 1] = u.y; bw[4 * j + 2] = u.z; bw[4 * j + 3] = u.w;
        }
    }

    size_t rowbase = (size_t)d * 8 + gl;
    H4 xh = ld4(B16, rowbase);
    H4 as = ld4(A16, rowbase);

    // self loop seeds online-softmax state
    float t = logit8(as, xh, awf, ns2);
    t += __shfl_xor(t, 1); t += __shfl_xor(t, 2); t += __shfl_xor(t, 4);
    float m = t, denom = 1.0f;
    float acc[8];
    #pragma unroll
    for (int j = 0; j < 4; ++j) {
        acc[2 * j] = (float)as.h[j].x;
        acc[2 * j + 1] = (float)as.h[j].y;
    }

    int lo = row_off[d], hi = row_off[d + 1];
    int k = lo;
    for (; k + 3 < hi; k += 4) {
        int s0 = csr_src[k], s1 = csr_src[k + 1], s2 = csr_src[k + 2], s3 = csr_src[k + 3];
        H4 a0 = ld4(A16, (size_t)s0 * 8 + gl);
        H4 a1 = ld4(A16, (size_t)s1 * 8 + gl);
        H4 a2 = ld4(A16, (size_t)s2 * 8 + gl);
        H4 a3 = ld4(A16, (size_t)s3 * 8 + gl);
        float t0 = logit8(a0, xh, awf, ns2);
        float t1 = logit8(a1, xh, awf, ns2);
        float t2 = logit8(a2, xh, awf, ns2);
        float t3 = logit8(a3, xh, awf, ns2);
        t0 += __shfl_xor(t0, 1); t1 += __shfl_xor(t1, 1);
        t2 += __shfl_xor(t2, 1); t3 += __shfl_xor(t3, 1);
        t0 += __shfl_xor(t0, 2); t1 += __shfl_xor(t1, 2);
        t2 += __shfl_xor(t2, 2); t3 += __shfl_xor(t3, 2);
        t0 += __shfl_xor(t0, 4); t1 += __shfl_xor(t1, 4);
        t2 += __shfl_xor(t2, 4); t3 += __shfl_xor(t3, 4);
        float mx = fmaxf(fmaxf(t0, t1), fmaxf(t2, t3));
        if (mx > m) {
            float sc = __expf(m - mx);
            denom *= sc;
            #pragma unroll
            for (int j = 0; j < 8; ++j) acc[j] *= sc;
            m = mx;
        }
        float w0 = __expf(t0 - m), w1 = __expf(t1 - m);
        float w2 = __expf(t2 - m), w3 = __expf(t3 - m);
        denom += (w0 + w1) + (w2 + w3);
        accum8(acc, a0, w0);
        accum8(acc, a1, w1);
        accum8(acc, a2, w2);
        accum8(acc, a3, w3);
    }
    for (; k < hi; ++k) {
        int s0 = csr_src[k];
        H4 a0 = ld4(A16, (size_t)s0 * 8 + gl);
        float t0 = logit8(a0, xh, awf, ns2);
        t0 += __shfl_xor(t0, 1); t0 += __shfl_xor(t0, 2); t0 += __shfl_xor(t0, 4);
        if (t0 > m) {
            float sc = __expf(m - t0);
            denom *= sc;
            #pragma unroll
            for (int j = 0; j < 8; ++j) acc[j] *= sc;
            m = t0;
        }
        float w0 = __expf(t0 - m);
        denom += w0;
        accum8(acc, a0, w0);
    }

    float inv = 1.0f / denom;
    float v[8];
    #pragma unroll
    for (int j = 0; j < 8; ++j) {
        v[j] = acc[j] * inv + bw[j];
        if (TANH) v[j] = tanhf(v[j]);
    }
    if constexpr (sizeof(OUT) == 2) {
        unsigned u[4];
        #pragma unroll
        for (int j = 0; j < 4; ++j) {
            f16x2 p; p.x = (_Float16)v[2 * j]; p.y = (_Float16)v[2 * j + 1];
            u[j] = __builtin_bit_cast(unsigned, p);
        }
        ((uint4*)out)[(size_t)d * 8 + gl] = make_uint4(u[0], u[1], u[2], u[3]);
    } else {
        float4* o4 = (float4*)out;
        o4[(size_t)d * 16 + gl * 2]     = make_float4(v[0], v[1], v[2], v[3]);
        o4[(size_t)d * 16 + gl * 2 + 1] = make_float4(v[4], v[5], v[6], v[7]);
    }
}

// ============ layer-2 transforms via MFMA ============

// prep: W (64x64 fp32, [k][c]) -> Wt (fp16, [c][k]) for B^T fragment loads
__global__ void k_wprep(const float* __restrict__ Wl, const float* __restrict__ Wr,
                        __half* __restrict__ Wtl, __half* __restrict__ Wtr) {
    int t = blockIdx.x * blockDim.x + threadIdx.x;
    if (t < 4096) {
        int c = t & 63, k = t >> 6;
        Wtl[(size_t)c * 64 + k] = __float2half(Wl[k * 64 + c]);
        Wtr[(size_t)c * 64 + k] = __float2half(Wr[k * 64 + c]);
    }
}

// each wave: 16 nodes x 64 ch for both tables; 16 x mfma_f32_16x16x32_f16.
__global__ __launch_bounds__(256) void k_xfrm2_mfma(
        const __half* __restrict__ H,
        const __half* __restrict__ Wtl, const __half* __restrict__ Wtr,
        const float* __restrict__ bl, const float* __restrict__ br,
        __half* __restrict__ A, __half* __restrict__ B, int N) {
    int wid = threadIdx.x >> 6;
    int lane = threadIdx.x & 63;
    int n0 = (blockIdx.x * 4 + wid) * 16;
    if (n0 >= N) return;
    int row = lane & 15, kg = lane >> 4;
    int nrow = n0 + row; if (nrow >= N) nrow = N - 1;   // clamp (loads only)

    const uint4* Hp = (const uint4*)(H + (size_t)nrow * HID + kg * 8);
    f16x8 af0 = __builtin_bit_cast(f16x8, Hp[0]);       // k = kg*8 .. +7
    f16x8 af1 = __builtin_bit_cast(f16x8, Hp[4]);       // k = 32 + kg*8 .. +7

    #pragma unroll
    for (int tb = 0; tb < 2; ++tb) {
        const __half* Wt = tb ? Wtr : Wtl;
        const float* bb  = tb ? br : bl;
        __half* OT       = tb ? B : A;
        #pragma unroll
        for (int ct = 0; ct < 4; ++ct) {
            int c = ct * 16 + row;
            const uint4* Wp = (const uint4*)(Wt + (size_t)c * HID + kg * 8);
            f16x8 bf0 = __builtin_bit_cast(f16x8, Wp[0]);
            f16x8 bf1 = __builtin_bit_cast(f16x8, Wp[4]);
            f32x4 acc = {0.f, 0.f, 0.f, 0.f};
            acc = __builtin_amdgcn_mfma_f32_16x16x32_f16(af0, bf0, acc, 0, 0, 0);
            acc = __builtin_amdgcn_mfma_f32_16x16x32_f16(af1, bf1, acc, 0, 0, 0);
            float bias = bb[c];
            #pragma unroll
            for (int r = 0; r < 4; ++r) {
                int node = n0 + kg * 4 + r;
                if (node < N) OT[(size_t)node * HID + c] = __float2half(acc[r] + bias);
            }
        }
    }
}

// fused pool + final linear: one wave per graph; binary-search bounds from sorted batch
__global__ void k_pool_final(const __half* __restrict__ C, const float* __restrict__ b2,
                             const int* __restrict__ batch,
                             const float* __restrict__ W3, const float* __restrict__ b3,
                             float* __restrict__ out, int N, int G) {
    int w = (int)((blockIdx.x * (size_t)blockDim.x + threadIdx.x) >> 6);
    int lane = threadIdx.x & 63;
    if (w >= G) return;
    int lo = 0, hi = N;
    while (lo < hi) { int mid = (lo + hi) >> 1; if (batch[mid] < w) lo = mid + 1; else hi = mid; }
    int s0 = lo;
    hi = N;
    while (lo < hi) { int mid = (lo + hi) >> 1; if (batch[mid] < w + 1) lo = mid + 1; else hi = mid; }
    int e0 = lo;

    float acc = -INFINITY;
    int i = s0;
    for (; i + 3 < e0; i += 4) {
        float v0 = __half2float(C[(size_t)i * HID + lane]);
        float v1 = __half2float(C[(size_t)(i + 1) * HID + lane]);
        float v2 = __half2float(C[(size_t)(i + 2) * HID + lane]);
        float v3 = __half2float(C[(size_t)(i + 3) * HID + lane]);
        acc = fmaxf(acc, fmaxf(fmaxf(v0, v1), fmaxf(v2, v3)));
    }
    for (; i < e0; ++i) acc = fmaxf(acc, __half2float(C[(size_t)i * HID + lane]));
    float v = acc + b2[lane];

    float p0 = v * W3[lane * 2];
    float p1 = v * W3[lane * 2 + 1];
    #pragma unroll
    for (int o = 32; o; o >>= 1) { p0 += __shfl_xor(p0, o); p1 += __shfl_xor(p1, o); }
    if (lane == 0) {
        out[(size_t)w * 2]     = p0 + b3[0];
        out[(size_t)w * 2 + 1] = p1 + b3[1];
    }
}

extern "C" void kernel_launch(void* const* d_in, const int* in_sizes, int n_in,
                              void* d_out, int out_size, void* d_ws, size_t ws_size,
                              hipStream_t stream) {
    const float* x     = (const float*)d_in[0];
    const int*   ei    = (const int*)d_in[1];
    const int*   batch = (const int*)d_in[2];
    const float* Wl1 = (const float*)d_in[3];
    const float* bl1 = (const float*)d_in[4];
    const float* Wr1 = (const float*)d_in[5];
    const float* br1 = (const float*)d_in[6];
    const float* a1  = (const float*)d_in[7];
    const float* b1  = (const float*)d_in[8];
    const float* Wl2 = (const float*)d_in[9];
    const float* bl2 = (const float*)d_in[10];
    const float* Wr2 = (const float*)d_in[11];
    const float* br2 = (const float*)d_in[12];
    const float* a2  = (const float*)d_in[13];
    const float* b2  = (const float*)d_in[14];
    const float* W3  = (const float*)d_in[15];
    const float* b3  = (const float*)d_in[16];

    const int N = in_sizes[0];          // 100000
    const int E = in_sizes[1] / 2;      // 1600000
    const int G = out_size / 2;         // 1000
    const int NB = (N + 255) >> 8;                 // 391 node bins
    const int NBLK = (E + BLK_E - 1) / BLK_E;      // 391 edge blocks

    // ---- workspace layout ----
    float* ws = (float*)d_ws;
    size_t off = 0;
    float*  C  = ws + off; off += (size_t)N * HID;  // sort temporaries + fp16 C overlay
    __half* Ah = (__half*)(ws + off); off += (size_t)N * HID / 2;
    __half* Bh = (__half*)(ws + off); off += (size_t)N * HID / 2;
    int*   row_off = (int*)(ws + off); off += N + 1;
    int*   csr_src = (int*)(ws + off); off += E;
    float* deg_in  = ws + off; off += N;
    int*   perm    = (int*)(ws + off); off += N;
    int*   dhist   = (int*)(ws + off); off += 1024;
    int*   bsS  = (int*)(ws + off); off += NB + 1;
    int*   bsD  = (int*)(ws + off); off += NB + 1;
    int*   totS = (int*)(ws + off); off += NB;
    int*   totD = (int*)(ws + off); off += NB;
    off = (off + 3) & ~(size_t)3;                   // 16B align for fp16 uint4 loads
    __half* Wtl = (__half*)(ws + off); off += 2048;
    __half* Wtr = (__half*)(ws + off); off += 2048;

    unsigned* packD = (unsigned*)C;
    unsigned* packS = packD + E;
    int* histS = (int*)(packS + E);
    int* histD = histS + (size_t)NB * NBLK;
    __half* Chalf = (__half*)C;       // layer-1 & layer-2 node features (fp16)

    const int* src  = ei;
    const int* dstp = ei + E;

    const int BT = 256;
    dim3 blk(BT);
    int grid_g8 = (int)(((size_t)N * 8 + BT - 1) / BT);
    int grid_mf = (N + 63) / 64;      // 4 waves/block x 16 nodes/wave

    // ---- CSR build via counting sort (no global atomics) ----
    k_hist2<<<NBLK, 1024, 0, stream>>>(src, dstp, histS, histD, E, NB, NBLK);
    k_binscan<<<2 * NB, 512, 0, stream>>>(histS, histD, totS, totD, NB, NBLK);
    k_binoffset<<<1, 512, 0, stream>>>(totS, totD, bsS, bsD, NB, E, row_off, N);
    k_scatter_bins<<<NBLK, 1024, 0, stream>>>(src, dstp, histS, histD, bsS, bsD,
                                              packS, packD, E, NB, NBLK);
    // fused: CSR finalize + deg_out count + layer-1 transforms
    k_csr_bin_fused<<<NB, 1024, 0, stream>>>(packD, bsD, packS, bsS, row_off, deg_in,
                                             csr_src, x, Wl1, bl1, Wr1, br1, Ah, Bh, N);

    // ---- degree-sorted node permutation (scheduling only) + W2 prep ----
    k_deghist<<<NDB, 1024, 0, stream>>>(deg_in, dhist, N);
    k_degscan<<<1, 1024, 0, stream>>>(dhist);
    k_degscatter<<<NDB, 1024, 0, stream>>>(deg_in, dhist, perm, N);
    k_wprep<<<16, 256, 0, stream>>>(Wl2, Wr2, Wtl, Wtr);

    // ---- layer 1 (fp16 output) ----
    k_gat_fused<__half, true><<<grid_g8, blk, 0, stream>>>(csr_src, row_off, perm,
                                                           Ah, Bh, a1, b1, Chalf, N);

    // ---- layer 2 (MFMA transforms, fp16 output) ----
    k_xfrm2_mfma<<<grid_mf, 256, 0, stream>>>(Chalf, Wtl, Wtr, bl2, br2, Ah, Bh, N);
    k_gat_fused<__half, false><<<grid_g8, blk, 0, stream>>>(csr_src, row_off, perm,
                                                            Ah, Bh, a2, b2, Chalf, N);

    // ---- fused pool + final linear ----
    k_pool_final<<<(G * 64 + BT - 1) / BT, blk, 0, stream>>>(Chalf, b2, batch, W3, b3,
                                                             (float*)d_out, N, G);
}

// Round 17
// 199.560 us; speedup vs baseline: 1.0913x; 1.0075x over previous
//
#include <hip/hip_runtime.h>
#include <hip/hip_bf16.h>
#include <hip/hip_fp16.h>

#define HID 64
#define NEG_SLOPE 0.2f
#define BLK_E 4096        // edges per block in binning passes
#define EDGE_CAP 6144     // LDS edge cache per bin
#define NDB 16            // blocks for degree sort

typedef _Float16 f16x2 __attribute__((ext_vector_type(2)));
typedef _Float16 f16x8 __attribute__((ext_vector_type(8)));
typedef float f32x4 __attribute__((ext_vector_type(4)));

// ============ counting-sort CSR build (no global atomics) ============

__global__ void k_hist2(const int* __restrict__ src, const int* __restrict__ dst,
                        int* __restrict__ histS, int* __restrict__ histD,
                        int E, int NB, int NBLK) {
    __shared__ int hs[512], hd[512];
    int t = threadIdx.x, blk = blockIdx.x;
    for (int b = t; b < NB; b += 1024) { hs[b] = 0; hd[b] = 0; }
    __syncthreads();
    int base = blk * BLK_E;
    #pragma unroll
    for (int k = 0; k < BLK_E / 1024; ++k) {
        int i = base + k * 1024 + t;
        if (i < E) {
            atomicAdd(&hs[src[i] >> 8], 1);
            atomicAdd(&hd[dst[i] >> 8], 1);
        }
    }
    __syncthreads();
    for (int b = t; b < NB; b += 1024) {
        histS[b * NBLK + blk] = hs[b];
        histD[b * NBLK + blk] = hd[b];
    }
}

// per-bin scan over blocks (NBLK <= 512)
__global__ void k_binscan(int* __restrict__ histS, int* __restrict__ histD,
                          int* __restrict__ totS, int* __restrict__ totD,
                          int NB, int NBLK) {
    __shared__ int s[512];
    int b = blockIdx.x;
    int* hist = histS; int* tot = totS;
    if (b >= NB) { b -= NB; hist = histD; tot = totD; }
    int t = threadIdx.x;
    int v = (t < NBLK) ? hist[b * NBLK + t] : 0;
    s[t] = v;
    __syncthreads();
    for (int o = 1; o < 512; o <<= 1) {
        int u = (t >= o) ? s[t - o] : 0;
        __syncthreads();
        s[t] += u;
        __syncthreads();
    }
    if (t < NBLK) hist[b * NBLK + t] = s[t] - v;
    if (t == 511) tot[b] = s[511];
}

__global__ void k_binoffset(const int* __restrict__ totS, const int* __restrict__ totD,
                            int* __restrict__ bsS, int* __restrict__ bsD,
                            int NB, int E, int* __restrict__ row_off, int N) {
    __shared__ int s[512];
    int t = threadIdx.x;
    int v = (t < NB) ? totS[t] : 0;
    s[t] = v; __syncthreads();
    for (int o = 1; o < 512; o <<= 1) {
        int u = (t >= o) ? s[t - o] : 0;
        __syncthreads(); s[t] += u; __syncthreads();
    }
    if (t < NB) bsS[t] = s[t] - v;
    if (t == 0) bsS[NB] = E;
    __syncthreads();
    v = (t < NB) ? totD[t] : 0;
    s[t] = v; __syncthreads();
    for (int o = 1; o < 512; o <<= 1) {
        int u = (t >= o) ? s[t - o] : 0;
        __syncthreads(); s[t] += u; __syncthreads();
    }
    if (t < NB) bsD[t] = s[t] - v;
    if (t == 0) { bsD[NB] = E; row_off[N] = E; }
}

__global__ void k_scatter_bins(const int* __restrict__ src, const int* __restrict__ dst,
                               const int* __restrict__ histS, const int* __restrict__ histD,
                               const int* __restrict__ bsS, const int* __restrict__ bsD,
                               unsigned char* __restrict__ packS, unsigned* __restrict__ packD,
                               int E, int NB, int NBLK) {
    __shared__ int baseS[512], baseD[512];
    int t = threadIdx.x, blk = blockIdx.x;
    for (int b = t; b < NB; b += 1024) {
        baseS[b] = bsS[b] + histS[b * NBLK + blk];
        baseD[b] = bsD[b] + histD[b * NBLK + blk];
    }
    __syncthreads();
    int base = blk * BLK_E;
    #pragma unroll
    for (int k = 0; k < BLK_E / 1024; ++k) {
        int i = base + k * 1024 + t;
        if (i < E) {
            int sv = src[i], dv = dst[i];
            int pD = atomicAdd(&baseD[dv >> 8], 1);
            packD[pD] = ((unsigned)(dv & 255) << 24) | (unsigned)sv;
            int pS = atomicAdd(&baseS[sv >> 8], 1);
            packS[pS] = (unsigned char)(sv & 255);
        }
    }
}

// fused: per-bin CSR finalize (deg_in, row_off, sorted csr_src) + src-side count
// (deg_out) + layer-1 transforms (A,B fp16) for the bin's 256 nodes.
__global__ void k_csr_bin_fused(const unsigned* __restrict__ packD, const int* __restrict__ bsD,
                                const unsigned char* __restrict__ packS, const int* __restrict__ bsS,
                                int* __restrict__ row_off, float* __restrict__ deg_in,
                                int* __restrict__ csr_src,
                                const float* __restrict__ x,
                                const float* __restrict__ Wl, const float* __restrict__ bl,
                                const float* __restrict__ Wr, const float* __restrict__ br,
                                __half* __restrict__ A, __half* __restrict__ B, int N) {
    __shared__ int cnt[256], off[256], cur[256], cntS[256];
    __shared__ unsigned eb[EDGE_CAP];
    int b = blockIdx.x, t = threadIdx.x;
    int lo = bsD[b], hi = bsD[b + 1], ne = hi - lo;
    bool fits = (ne <= EDGE_CAP);
    if (t < 256) { cnt[t] = 0; cntS[t] = 0; }
    __syncthreads();
    for (int i = t; i < ne; i += 1024) {
        unsigned v = packD[lo + i];
        if (fits) eb[i] = v;
        atomicAdd(&cnt[v >> 24], 1);
    }
    int loS = bsS[b], hiS = bsS[b + 1];
    for (int i = loS + t; i < hiS; i += 1024) atomicAdd(&cntS[packS[i]], 1);
    __syncthreads();
    if (t < 256) off[t] = cnt[t];
    __syncthreads();
    for (int o = 1; o < 256; o <<= 1) {
        int u = 0;
        if (t < 256 && t >= o) u = off[t - o];
        __syncthreads();
        if (t < 256) off[t] += u;
        __syncthreads();
    }
    if (t < 256) {
        int ex = off[t] - cnt[t];
        cur[t] = lo + ex;
        int node = b * 256 + t;
        if (node < N) {
            row_off[node] = lo + ex;
            deg_in[node] = (float)cnt[t];
        }
    }
    __syncthreads();
    for (int i = t; i < ne; i += 1024) {
        unsigned v = fits ? eb[i] : packD[lo + i];
        int pos = atomicAdd(&cur[v >> 24], 1);
        csr_src[pos] = (int)(v & 0xFFFFFFu);
    }
    // ---- fused layer-1 transform for this bin's nodes ----
    int nd = b * 256 + (t >> 2);
    if (nd < N) {
        float h0 = x[nd];
        float h1 = (float)cnt[t >> 2];
        float h2 = (float)cntS[t >> 2];
        int c0 = (t & 3) * 16;
        unsigned ua[4], ub[4];
        #pragma unroll
        for (int p = 0; p < 2; ++p) {
            #pragma unroll
            for (int q = 0; q < 4; ++q) {
                int c = c0 + p * 8 + q * 2;
                float a0 = h0 * Wl[c]     + h1 * Wl[64 + c]     + h2 * Wl[128 + c]     + bl[c];
                float a1 = h0 * Wl[c + 1] + h1 * Wl[64 + c + 1] + h2 * Wl[128 + c + 1] + bl[c + 1];
                float b0 = h0 * Wr[c]     + h1 * Wr[64 + c]     + h2 * Wr[128 + c]     + br[c];
                float b1 = h0 * Wr[c + 1] + h1 * Wr[64 + c + 1] + h2 * Wr[128 + c + 1] + br[c + 1];
                f16x2 pa; pa.x = (_Float16)a0; pa.y = (_Float16)a1;
                f16x2 pb; pb.x = (_Float16)b0; pb.y = (_Float16)b1;
                ua[q] = __builtin_bit_cast(unsigned, pa);
                ub[q] = __builtin_bit_cast(unsigned, pb);
            }
            uint4 sa = make_uint4(ua[0], ua[1], ua[2], ua[3]);
            uint4 sb = make_uint4(ub[0], ub[1], ub[2], ub[3]);
            ((uint4*)A)[(size_t)nd * 8 + (t & 3) * 2 + p] = sa;
            ((uint4*)B)[(size_t)nd * 8 + (t & 3) * 2 + p] = sb;
        }
    }
}

// ============ degree sort (perm only changes scheduling, not any FP result) ============

__global__ void k_deghist(const float* __restrict__ deg_in, int* __restrict__ dhist, int N) {
    __shared__ int h[64];
    int t = threadIdx.x, b = blockIdx.x;
    if (t < 64) h[t] = 0;
    __syncthreads();
    int chunk = (N + NDB - 1) / NDB;
    int lo = b * chunk, hi = lo + chunk; if (hi > N) hi = N;
    for (int i = lo + t; i < hi; i += 1024) {
        int dg = (int)deg_in[i]; if (dg > 63) dg = 63;
        atomicAdd(&h[dg], 1);
    }
    __syncthreads();
    if (t < 64) dhist[t * NDB + b] = h[t];
}

__global__ void k_degscan(int* __restrict__ dhist) {
    __shared__ int s[1024];
    int t = threadIdx.x;
    int v = dhist[t];
    s[t] = v; __syncthreads();
    for (int o = 1; o < 1024; o <<= 1) {
        int u = (t >= o) ? s[t - o] : 0;
        __syncthreads(); s[t] += u; __syncthreads();
    }
    dhist[t] = s[t] - v;
}

__global__ void k_degscatter(const float* __restrict__ deg_in, const int* __restrict__ dhist,
                             int* __restrict__ perm, int N) {
    __shared__ int cur[64];
    int t = threadIdx.x, b = blockIdx.x;
    if (t < 64) cur[t] = dhist[t * NDB + b];
    __syncthreads();
    int chunk = (N + NDB - 1) / NDB;
    int lo = b * chunk, hi = lo + chunk; if (hi > N) hi = N;
    for (int i = lo + t; i < hi; i += 1024) {
        int dg = (int)deg_in[i]; if (dg > 63) dg = 63;
        int p = atomicAdd(&cur[dg], 1);
        perm[p] = i;
    }
}

// ============ fused GAT layer: 8 lanes per dst node (8 ch each) ============

struct H4 { f16x2 h[4]; };

__device__ __forceinline__ f16x2 bch2(unsigned u) {
    return __builtin_bit_cast(f16x2, u);
}

__device__ __forceinline__ H4 ld4(const uint4* __restrict__ T, size_t idx) {
    uint4 r = T[idx];
    H4 o;
    o.h[0] = bch2(r.x); o.h[1] = bch2(r.y); o.h[2] = bch2(r.z); o.h[3] = bch2(r.w);
    return o;
}

// 8-channel partial logit
__device__ __forceinline__ float logit8(const H4& a, const H4& x,
                                        const float* __restrict__ awf, f16x2 ns2) {
    float t = 0.0f;
    #pragma unroll
    for (int j = 0; j < 4; ++j) {
        f16x2 s = a.h[j] + x.h[j];
        f16x2 l = __builtin_elementwise_max(s, ns2 * s);
        t = fmaf((float)l.x, awf[2 * j], t);
        t = fmaf((float)l.y, awf[2 * j + 1], t);
    }
    return t;
}

__device__ __forceinline__ void accum8(float* __restrict__ acc, const H4& a, float w) {
    #pragma unroll
    for (int j = 0; j < 4; ++j) {
        acc[2 * j]     = fmaf((float)a.h[j].x, w, acc[2 * j]);
        acc[2 * j + 1] = fmaf((float)a.h[j].y, w, acc[2 * j + 1]);
    }
}

template <typename OUT, bool TANH>
__global__ void k_gat_fused(const int* __restrict__ csr_src, const int* __restrict__ row_off,
                            const int* __restrict__ perm,
                            const __half* __restrict__ Ah, const __half* __restrict__ Bh,
                            const float* __restrict__ aw, const float* __restrict__ bias,
                            OUT* __restrict__ out, int N) {
    int tid = blockIdx.x * blockDim.x + threadIdx.x;
    int r = tid >> 3;
    int gl = threadIdx.x & 7;
    if (r >= N) return;
    int d = perm[N - 1 - r];   // descending degree

    const uint4* A16 = (const uint4*)Ah;
    const uint4* B16 = (const uint4*)Bh;
    f16x2 ns2;
    ns2.x = (_Float16)NEG_SLOPE; ns2.y = (_Float16)NEG_SLOPE;

    float awf[8], bw[8];
    {
        const float4* a4 = (const float4*)aw;
        const float4* b4 = (const float4*)bias;
        #pragma unroll
        for (int j = 0; j < 2; ++j) {
            float4 v = a4[gl * 2 + j];
            awf[4 * j] = v.x; awf[4 * j + 1] = v.y; awf[4 * j + 2] = v.z; awf[4 * j + 3] = v.w;
            float4 u = b4[gl * 2 + j];
            bw[4 * j] = u.x; bw[4 * j + 1] = u.y; bw[4 * j + 2] = u.z; bw[4 * j + 3] = u.w;
        }
    }

    size_t rowbase = (size_t)d * 8 + gl;
    H4 xh = ld4(B16, rowbase);
    H4 as = ld4(A16, rowbase);

    // self loop seeds online-softmax state
    float t = logit8(as, xh, awf, ns2);
    t += __shfl_xor(t, 1); t += __shfl_xor(t, 2); t += __shfl_xor(t, 4);
    float m = t, denom = 1.0f;
    float acc[8];
    #pragma unroll
    for (int j = 0; j < 4; ++j) {
        acc[2 * j] = (float)as.h[j].x;
        acc[2 * j + 1] = (float)as.h[j].y;
    }

    int lo = row_off[d], hi = row_off[d + 1];
    int k = lo;
    for (; k + 3 < hi; k += 4) {
        int s0 = csr_src[k], s1 = csr_src[k + 1], s2 = csr_src[k + 2], s3 = csr_src[k + 3];
        H4 a0 = ld4(A16, (size_t)s0 * 8 + gl);
        H4 a1 = ld4(A16, (size_t)s1 * 8 + gl);
        H4 a2 = ld4(A16, (size_t)s2 * 8 + gl);
        H4 a3 = ld4(A16, (size_t)s3 * 8 + gl);
        float t0 = logit8(a0, xh, awf, ns2);
        float t1 = logit8(a1, xh, awf, ns2);
        float t2 = logit8(a2, xh, awf, ns2);
        float t3 = logit8(a3, xh, awf, ns2);
        t0 += __shfl_xor(t0, 1); t1 += __shfl_xor(t1, 1);
        t2 += __shfl_xor(t2, 1); t3 += __shfl_xor(t3, 1);
        t0 += __shfl_xor(t0, 2); t1 += __shfl_xor(t1, 2);
        t2 += __shfl_xor(t2, 2); t3 += __shfl_xor(t3, 2);
        t0 += __shfl_xor(t0, 4); t1 += __shfl_xor(t1, 4);
        t2 += __shfl_xor(t2, 4); t3 += __shfl_xor(t3, 4);
        float mx = fmaxf(fmaxf(t0, t1), fmaxf(t2, t3));
        if (mx > m) {
            float sc = __expf(m - mx);
            denom *= sc;
            #pragma unroll
            for (int j = 0; j < 8; ++j) acc[j] *= sc;
            m = mx;
        }
        float w0 = __expf(t0 - m), w1 = __expf(t1 - m);
        float w2 = __expf(t2 - m), w3 = __expf(t3 - m);
        denom += (w0 + w1) + (w2 + w3);
        accum8(acc, a0, w0);
        accum8(acc, a1, w1);
        accum8(acc, a2, w2);
        accum8(acc, a3, w3);
    }
    for (; k < hi; ++k) {
        int s0 = csr_src[k];
        H4 a0 = ld4(A16, (size_t)s0 * 8 + gl);
        float t0 = logit8(a0, xh, awf, ns2);
        t0 += __shfl_xor(t0, 1); t0 += __shfl_xor(t0, 2); t0 += __shfl_xor(t0, 4);
        if (t0 > m) {
            float sc = __expf(m - t0);
            denom *= sc;
            #pragma unroll
            for (int j = 0; j < 8; ++j) acc[j] *= sc;
            m = t0;
        }
        float w0 = __expf(t0 - m);
        denom += w0;
        accum8(acc, a0, w0);
    }

    float inv = 1.0f / denom;
    float v[8];
    #pragma unroll
    for (int j = 0; j < 8; ++j) {
        v[j] = acc[j] * inv + bw[j];
        if (TANH) v[j] = tanhf(v[j]);
    }
    if constexpr (sizeof(OUT) == 2) {
        unsigned u[4];
        #pragma unroll
        for (int j = 0; j < 4; ++j) {
            f16x2 p; p.x = (_Float16)v[2 * j]; p.y = (_Float16)v[2 * j + 1];
            u[j] = __builtin_bit_cast(unsigned, p);
        }
        ((uint4*)out)[(size_t)d * 8 + gl] = make_uint4(u[0], u[1], u[2], u[3]);
    } else {
        float4* o4 = (float4*)out;
        o4[(size_t)d * 16 + gl * 2]     = make_float4(v[0], v[1], v[2], v[3]);
        o4[(size_t)d * 16 + gl * 2 + 1] = make_float4(v[4], v[5], v[6], v[7]);
    }
}

// ============ layer-2 transforms via MFMA ============

// prep: W (64x64 fp32, [k][c]) -> Wt (fp16, [c][k]) for B^T fragment loads
__global__ void k_wprep(const float* __restrict__ Wl, const float* __restrict__ Wr,
                        __half* __restrict__ Wtl, __half* __restrict__ Wtr) {
    int t = blockIdx.x * blockDim.x + threadIdx.x;
    if (t < 4096) {
        int c = t & 63, k = t >> 6;
        Wtl[(size_t)c * 64 + k] = __float2half(Wl[k * 64 + c]);
        Wtr[(size_t)c * 64 + k] = __float2half(Wr[k * 64 + c]);
    }
}

// each wave: 16 nodes x 64 ch for both tables; 16 x mfma_f32_16x16x32_f16.
__global__ __launch_bounds__(256) void k_xfrm2_mfma(
        const __half* __restrict__ H,
        const __half* __restrict__ Wtl, const __half* __restrict__ Wtr,
        const float* __restrict__ bl, const float* __restrict__ br,
        __half* __restrict__ A, __half* __restrict__ B, int N) {
    int wid = threadIdx.x >> 6;
    int lane = threadIdx.x & 63;
    int n0 = (blockIdx.x * 4 + wid) * 16;
    if (n0 >= N) return;
    int row = lane & 15, kg = lane >> 4;
    int nrow = n0 + row; if (nrow >= N) nrow = N - 1;   // clamp (loads only)

    const uint4* Hp = (const uint4*)(H + (size_t)nrow * HID + kg * 8);
    f16x8 af0 = __builtin_bit_cast(f16x8, Hp[0]);       // k = kg*8 .. +7
    f16x8 af1 = __builtin_bit_cast(f16x8, Hp[4]);       // k = 32 + kg*8 .. +7

    #pragma unroll
    for (int tb = 0; tb < 2; ++tb) {
        const __half* Wt = tb ? Wtr : Wtl;
        const float* bb  = tb ? br : bl;
        __half* OT       = tb ? B : A;
        #pragma unroll
        for (int ct = 0; ct < 4; ++ct) {
            int c = ct * 16 + row;
            const uint4* Wp = (const uint4*)(Wt + (size_t)c * HID + kg * 8);
            f16x8 bf0 = __builtin_bit_cast(f16x8, Wp[0]);
            f16x8 bf1 = __builtin_bit_cast(f16x8, Wp[4]);
            f32x4 acc = {0.f, 0.f, 0.f, 0.f};
            acc = __builtin_amdgcn_mfma_f32_16x16x32_f16(af0, bf0, acc, 0, 0, 0);
            acc = __builtin_amdgcn_mfma_f32_16x16x32_f16(af1, bf1, acc, 0, 0, 0);
            float bias = bb[c];
            #pragma unroll
            for (int r = 0; r < 4; ++r) {
                int node = n0 + kg * 4 + r;
                if (node < N) OT[(size_t)node * HID + c] = __float2half(acc[r] + bias);
            }
        }
    }
}

// fused pool + final linear: one wave per graph; binary-search bounds from sorted batch
__global__ void k_pool_final(const __half* __restrict__ C, const float* __restrict__ b2,
                             const int* __restrict__ batch,
                             const float* __restrict__ W3, const float* __restrict__ b3,
                             float* __restrict__ out, int N, int G) {
    int w = (int)((blockIdx.x * (size_t)blockDim.x + threadIdx.x) >> 6);
    int lane = threadIdx.x & 63;
    if (w >= G) return;
    int lo = 0, hi = N;
    while (lo < hi) { int mid = (lo + hi) >> 1; if (batch[mid] < w) lo = mid + 1; else hi = mid; }
    int s0 = lo;
    hi = N;
    while (lo < hi) { int mid = (lo + hi) >> 1; if (batch[mid] < w + 1) lo = mid + 1; else hi = mid; }
    int e0 = lo;

    float acc = -INFINITY;
    int i = s0;
    for (; i + 3 < e0; i += 4) {
        float v0 = __half2float(C[(size_t)i * HID + lane]);
        float v1 = __half2float(C[(size_t)(i + 1) * HID + lane]);
        float v2 = __half2float(C[(size_t)(i + 2) * HID + lane]);
        float v3 = __half2float(C[(size_t)(i + 3) * HID + lane]);
        acc = fmaxf(acc, fmaxf(fmaxf(v0, v1), fmaxf(v2, v3)));
    }
    for (; i < e0; ++i) acc = fmaxf(acc, __half2float(C[(size_t)i * HID + lane]));
    float v = acc + b2[lane];

    float p0 = v * W3[lane * 2];
    float p1 = v * W3[lane * 2 + 1];
    #pragma unroll
    for (int o = 32; o; o >>= 1) { p0 += __shfl_xor(p0, o); p1 += __shfl_xor(p1, o); }
    if (lane == 0) {
        out[(size_t)w * 2]     = p0 + b3[0];
        out[(size_t)w * 2 + 1] = p1 + b3[1];
    }
}

extern "C" void kernel_launch(void* const* d_in, const int* in_sizes, int n_in,
                              void* d_out, int out_size, void* d_ws, size_t ws_size,
                              hipStream_t stream) {
    const float* x     = (const float*)d_in[0];
    const int*   ei    = (const int*)d_in[1];
    const int*   batch = (const int*)d_in[2];
    const float* Wl1 = (const float*)d_in[3];
    const float* bl1 = (const float*)d_in[4];
    const float* Wr1 = (const float*)d_in[5];
    const float* br1 = (const float*)d_in[6];
    const float* a1  = (const float*)d_in[7];
    const float* b1  = (const float*)d_in[8];
    const float* Wl2 = (const float*)d_in[9];
    const float* bl2 = (const float*)d_in[10];
    const float* Wr2 = (const float*)d_in[11];
    const float* br2 = (const float*)d_in[12];
    const float* a2  = (const float*)d_in[13];
    const float* b2  = (const float*)d_in[14];
    const float* W3  = (const float*)d_in[15];
    const float* b3  = (const float*)d_in[16];

    const int N = in_sizes[0];          // 100000
    const int E = in_sizes[1] / 2;      // 1600000
    const int G = out_size / 2;         // 1000
    const int NB = (N + 255) >> 8;                 // 391 node bins
    const int NBLK = (E + BLK_E - 1) / BLK_E;      // 391 edge blocks

    // ---- workspace layout ----
    float* ws = (float*)d_ws;
    size_t off = 0;
    float*  C  = ws + off; off += (size_t)N * HID;  // sort temporaries + fp16 C overlay
    __half* Ah = (__half*)(ws + off); off += (size_t)N * HID / 2;
    __half* Bh = (__half*)(ws + off); off += (size_t)N * HID / 2;
    int*   row_off = (int*)(ws + off); off += N + 1;
    int*   csr_src = (int*)(ws + off); off += E;
    float* deg_in  = ws + off; off += N;
    int*   perm    = (int*)(ws + off); off += N;
    int*   dhist   = (int*)(ws + off); off += 1024;
    int*   bsS  = (int*)(ws + off); off += NB + 1;
    int*   bsD  = (int*)(ws + off); off += NB + 1;
    int*   totS = (int*)(ws + off); off += NB;
    int*   totD = (int*)(ws + off); off += NB;
    off = (off + 3) & ~(size_t)3;                   // 16B align for fp16 uint4 loads
    __half* Wtl = (__half*)(ws + off); off += 2048;
    __half* Wtr = (__half*)(ws + off); off += 2048;

    unsigned* packD = (unsigned*)C;                  // E words
    unsigned char* packS = (unsigned char*)(packD + E);  // E bytes
    int* histS = (int*)(packS + ((E + 3) & ~3));
    int* histD = histS + (size_t)NB * NBLK;
    __half* Chalf = (__half*)C;       // layer-1 & layer-2 node features (fp16)

    const int* src  = ei;
    const int* dstp = ei + E;

    const int BT = 256;
    dim3 blk(BT);
    int grid_g8 = (int)(((size_t)N * 8 + BT - 1) / BT);
    int grid_mf = (N + 63) / 64;      // 4 waves/block x 16 nodes/wave

    // ---- CSR build via counting sort (no global atomics) ----
    k_hist2<<<NBLK, 1024, 0, stream>>>(src, dstp, histS, histD, E, NB, NBLK);
    k_binscan<<<2 * NB, 512, 0, stream>>>(histS, histD, totS, totD, NB, NBLK);
    k_binoffset<<<1, 512, 0, stream>>>(totS, totD, bsS, bsD, NB, E, row_off, N);
    k_scatter_bins<<<NBLK, 1024, 0, stream>>>(src, dstp, histS, histD, bsS, bsD,
                                              packS, packD, E, NB, NBLK);
    // fused: CSR finalize + deg_out count + layer-1 transforms
    k_csr_bin_fused<<<NB, 1024, 0, stream>>>(packD, bsD, packS, bsS, row_off, deg_in,
                                             csr_src, x, Wl1, bl1, Wr1, br1, Ah, Bh, N);

    // ---- degree-sorted node permutation (scheduling only) + W2 prep ----
    k_deghist<<<NDB, 1024, 0, stream>>>(deg_in, dhist, N);
    k_degscan<<<1, 1024, 0, stream>>>(dhist);
    k_degscatter<<<NDB, 1024, 0, stream>>>(deg_in, dhist, perm, N);
    k_wprep<<<16, 256, 0, stream>>>(Wl2, Wr2, Wtl, Wtr);

    // ---- layer 1 (fp16 output) ----
    k_gat_fused<__half, true><<<grid_g8, blk, 0, stream>>>(csr_src, row_off, perm,
                                                           Ah, Bh, a1, b1, Chalf, N);

    // ---- layer 2 (MFMA transforms, fp16 output) ----
    k_xfrm2_mfma<<<grid_mf, 256, 0, stream>>>(Chalf, Wtl, Wtr, bl2, br2, Ah, Bh, N);
    k_gat_fused<__half, false><<<grid_g8, blk, 0, stream>>>(csr_src, row_off, perm,
                                                            Ah, Bh, a2, b2, Chalf, N);

    // ---- fused pool + final linear ----
    k_pool_final<<<(G * 64 + BT - 1) / BT, blk, 0, stream>>>(Chalf, b2, batch, W3, b3,
                                                             (float*)d_out, N, G);
}